// Round 6
// baseline (46.060 us; speedup 1.0000x reference)
//
#include <hip/hip_runtime.h>

// YOLOv1 loss, MI355X. preds/targets: (16384,7,7,30) f32 -> 3 f32 losses.
// R6: lazy loads (R4 pattern, best so far), 2 cells/thread, 512-thread blocks
// -> 784 blocks, half the waves, tiny tail reduce. All structures move the
// same 192.6 MB line-granular traffic (~5 TB/s effective); this round attacks
// the remaining fixed overhead (tail + ramp + wave count).

constexpr int   CH      = 30;              // dwords per cell
constexpr int   NCELL   = 16384 * 7 * 7;   // 802816
constexpr int   BLK     = 512;
constexpr int   CPT     = 2;               // cells per thread
constexpr int   NBLK    = NCELL / (BLK * CPT);   // 784 exactly
constexpr float INV_GS  = 1.0f / 7.0f;
constexpr float INV_BS  = 1.0f / 16384.0f;
constexpr float L_COORD = 5.0f;
constexpr float L_NOOBJ = 0.5f;

// Per-cell loss, lazy loads. Adds into s_box/s_obj/s_cls.
__device__ __forceinline__ void cell_loss(
    const float* __restrict__ P, const float* __restrict__ T,
    float& s_box, float& s_obj, float& s_cls)
{
    const float t4 = T[4];
    const float p4 = P[4];
    const float p9 = P[9];
    const bool  obj = t4 > 0.f;

    if (obj) {
        const float p0 = P[0], p1 = P[1], p2 = P[2], p3 = P[3];
        const float p5 = P[5], p6 = P[6], p7 = P[7], p8 = P[8];
        const float t0 = T[0], t1 = T[1], t2 = T[2], t3 = T[3];

        const float tx = t0 * INV_GS, ty = t1 * INV_GS;
        const float tax0 = tx - 0.5f * t2, tay0 = ty - 0.5f * t3;
        const float tax1 = tx + 0.5f * t2, tay1 = ty + 0.5f * t3;
        const float area_t = t2 * t3;

        float iou0, iou1;
        {
            float px = p0 * INV_GS, py = p1 * INV_GS;
            float ax0 = px - 0.5f * p2, ay0 = py - 0.5f * p3;
            float ax1 = px + 0.5f * p2, ay1 = py + 0.5f * p3;
            float iw = fmaxf(fminf(ax1, tax1) - fmaxf(ax0, tax0), 0.f);
            float ih = fmaxf(fminf(ay1, tay1) - fmaxf(ay0, tay0), 0.f);
            float inter = iw * ih;
            iou0 = inter / (p2 * p3 + area_t - inter);
        }
        {
            float px = p5 * INV_GS, py = p6 * INV_GS;
            float ax0 = px - 0.5f * p7, ay0 = py - 0.5f * p8;
            float ax1 = px + 0.5f * p7, ay1 = py + 0.5f * p8;
            float iw = fmaxf(fminf(ax1, tax1) - fmaxf(ax0, tax0), 0.f);
            float ih = fmaxf(fminf(ay1, tay1) - fmaxf(ay0, tay0), 0.f);
            float inter = iw * ih;
            iou1 = inter / (p7 * p8 + area_t - inter);
        }

        const bool  sel     = iou1 > iou0;        // first-max tie-break
        const float max_iou = fmaxf(iou0, iou1);
        const float rx = sel ? p5 : p0;
        const float ry = sel ? p6 : p1;
        const float rw = sel ? p7 : p2;
        const float rh = sel ? p8 : p3;
        const float rc = sel ? p9 : p4;

        float dx = rx - t0, dy = ry - t1;
        float sw = sqrtf(rw) - sqrtf(t2);
        float sh = sqrtf(rh) - sqrtf(t3);
        s_box += dx * dx + dy * dy + sw * sw + sh * sh;

        float dc = rc - max_iou;
        s_obj += dc * dc;

        float acc = 0.f;
        #pragma unroll
        for (int k = 10; k < 30; ++k) {
            float d = P[k] - T[k];
            acc += d * d;
        }
        s_cls += acc;
    } else {
        // noobj: t[4]==t[9]==0 by construction
        s_obj += L_NOOBJ * (p4 * p4 + p9 * p9);
    }
}

__global__ __launch_bounds__(BLK) void yolo_loss_partial(
    const float* __restrict__ preds,
    const float* __restrict__ targets,
    float* __restrict__ part)   // [3][NBLK] raw sums
{
    const int n0 = (blockIdx.x * BLK + threadIdx.x) * CPT;
    const float* __restrict__ P = preds   + (size_t)n0 * CH;
    const float* __restrict__ T = targets + (size_t)n0 * CH;

    float s_box = 0.f, s_obj = 0.f, s_cls = 0.f;
    cell_loss(P,      T,      s_box, s_obj, s_cls);
    cell_loss(P + CH, T + CH, s_box, s_obj, s_cls);

    // --- wave + block reduce ---
    #pragma unroll
    for (int off = 32; off > 0; off >>= 1) {
        s_box += __shfl_down(s_box, off);
        s_obj += __shfl_down(s_obj, off);
        s_cls += __shfl_down(s_cls, off);
    }

    __shared__ float red[3][BLK / 64];
    const int wid  = threadIdx.x >> 6;
    const int lane = threadIdx.x & 63;
    if (lane == 0) { red[0][wid] = s_box; red[1][wid] = s_obj; red[2][wid] = s_cls; }
    __syncthreads();
    if (threadIdx.x == 0) {
        float b = 0.f, o = 0.f, c = 0.f;
        #pragma unroll
        for (int w = 0; w < BLK / 64; ++w) { b += red[0][w]; o += red[1][w]; c += red[2][w]; }
        part[0 * NBLK + blockIdx.x] = b;
        part[1 * NBLK + blockIdx.x] = o;
        part[2 * NBLK + blockIdx.x] = c;
    }
}

__global__ __launch_bounds__(256) void yolo_loss_reduce(
    const float* __restrict__ part, float* __restrict__ out)
{
    float s0 = 0.f, s1 = 0.f, s2 = 0.f;
    for (int i = threadIdx.x; i < NBLK; i += 256) {
        s0 += part[0 * NBLK + i];
        s1 += part[1 * NBLK + i];
        s2 += part[2 * NBLK + i];
    }
    #pragma unroll
    for (int off = 32; off > 0; off >>= 1) {
        s0 += __shfl_down(s0, off);
        s1 += __shfl_down(s1, off);
        s2 += __shfl_down(s2, off);
    }
    __shared__ float red[3][4];
    const int wid  = threadIdx.x >> 6;
    const int lane = threadIdx.x & 63;
    if (lane == 0) { red[0][wid] = s0; red[1][wid] = s1; red[2][wid] = s2; }
    __syncthreads();
    if (threadIdx.x == 0) {
        float b = red[0][0] + red[0][1] + red[0][2] + red[0][3];
        float o = red[1][0] + red[1][1] + red[1][2] + red[1][3];
        float c = red[2][0] + red[2][1] + red[2][2] + red[2][3];
        out[0] = L_COORD * b * INV_BS;
        out[1] = o * INV_BS;
        out[2] = c * INV_BS;
    }
}

extern "C" void kernel_launch(void* const* d_in, const int* in_sizes, int n_in,
                              void* d_out, int out_size, void* d_ws, size_t ws_size,
                              hipStream_t stream) {
    const float* preds   = (const float*)d_in[0];
    const float* targets = (const float*)d_in[1];
    float* out  = (float*)d_out;
    float* part = (float*)d_ws;   // 3*NBLK floats = 9408 B

    yolo_loss_partial<<<NBLK, BLK, 0, stream>>>(preds, targets, part);
    yolo_loss_reduce<<<1, 256, 0, stream>>>(part, out);
}